// Round 1
// baseline (847.362 us; speedup 1.0000x reference)
//
#include <hip/hip_runtime.h>
#include <hip/hip_bf16.h>

// MoE top-2/8: N=8192 tokens, C=1024, H=2048.
// K1: fp32 gating (exact expert selection) + x->bf16 + per-expert token lists.
// K2: grouped GEMM up&gate (shared A tile) + SiLU -> h (bf16, packed rows).
// K3: grouped GEMM down (h @ wo) * combine -> atomicAdd into zeroed out.
// ws layout: counts@0, tlist@1KB (8*8192 int), combine@263168 (8192*8 f32),
//            x_bf16@1MB (16MB), h@17825792 (64MB). Total ~81MB.

#define N_TOK 8192
#define C_DIM 1024
#define H_DIM 2048
#define E_NUM 8

typedef __attribute__((ext_vector_type(8))) short short8;
typedef __attribute__((ext_vector_type(4))) float f32x4;

__device__ __forceinline__ unsigned short f2bf(float f) {
    // round-to-nearest-even f32 -> bf16 (inputs finite)
    unsigned int u = __float_as_uint(f);
    unsigned int r = (u + 0x7FFFu + ((u >> 16) & 1u)) >> 16;
    return (unsigned short)r;
}

__device__ __forceinline__ f32x4 mfma16(short8 a, short8 b, f32x4 c) {
    return __builtin_amdgcn_mfma_f32_16x16x32_bf16(a, b, c, 0, 0, 0);
}

// ---------------- K1: gating ----------------
__global__ __launch_bounds__(256) void k_gate(
    const float* __restrict__ x, const float* __restrict__ wgate,
    int* __restrict__ counts, int* __restrict__ tlist,
    float* __restrict__ combine, unsigned short* __restrict__ xbf)
{
    int wid = threadIdx.x >> 6;
    int lane = threadIdx.x & 63;
    int token = blockIdx.x * 4 + wid;
    const float* xr = x + (size_t)token * C_DIM;
    unsigned short* xbr = xbf + (size_t)token * C_DIM;

    float p[E_NUM] = {0.f,0.f,0.f,0.f,0.f,0.f,0.f,0.f};
    #pragma unroll
    for (int i = 0; i < C_DIM / 64; ++i) {
        int c = i * 64 + lane;
        float xv = xr[c];
        xbr[c] = f2bf(xv);
        const float4* wr = reinterpret_cast<const float4*>(wgate + (size_t)c * E_NUM);
        float4 w0 = wr[0], w1 = wr[1];
        p[0] += xv * w0.x; p[1] += xv * w0.y; p[2] += xv * w0.z; p[3] += xv * w0.w;
        p[4] += xv * w1.x; p[5] += xv * w1.y; p[6] += xv * w1.z; p[7] += xv * w1.w;
    }
    #pragma unroll
    for (int e = 0; e < E_NUM; ++e) {
        #pragma unroll
        for (int s = 32; s > 0; s >>= 1) p[e] += __shfl_xor(p[e], s, 64);
    }
    if (lane == 0) {
        float m = p[0];
        #pragma unroll
        for (int e = 1; e < E_NUM; ++e) m = fmaxf(m, p[e]);
        float g[E_NUM]; float den = 0.f;
        #pragma unroll
        for (int e = 0; e < E_NUM; ++e) { g[e] = expf(p[e] - m); den += g[e]; }
        float inv = 1.f / den;
        #pragma unroll
        for (int e = 0; e < E_NUM; ++e) g[e] *= inv;
        // top-2, lowest index on ties (matches jax.lax.top_k)
        int i1 = 0;
        #pragma unroll
        for (int e = 1; e < E_NUM; ++e) if (g[e] > g[i1]) i1 = e;
        int i2 = (i1 == 0) ? 1 : 0;
        #pragma unroll
        for (int e = 0; e < E_NUM; ++e) if (e != i1 && g[e] > g[i2]) i2 = e;
        #pragma unroll
        for (int e = 0; e < E_NUM; ++e)
            combine[(size_t)token * E_NUM + e] = (e == i1 || e == i2) ? g[e] : 0.f;
        int p1 = atomicAdd(&counts[i1], 1);
        tlist[i1 * N_TOK + p1] = token;
        int p2 = atomicAdd(&counts[i2], 1);
        tlist[i2 * N_TOK + p2] = token;
    }
}

// ---------------- K2: up/gate GEMM + SiLU -> h ----------------
// tile: 128 rows x 64 cols (per output), BK=32, 4 waves (2x2)
__global__ __launch_bounds__(256) void k_upgate(
    const unsigned short* __restrict__ xbf,
    const float* __restrict__ Wi, const float* __restrict__ Wg,
    const int* __restrict__ counts, const int* __restrict__ tlist,
    unsigned short* __restrict__ hbuf)
{
    __shared__ unsigned short smem[10240]; // sA[128][40] + sB[2][64][40]; reused as h tile [128][72]
    int e = blockIdx.z;
    int cnt = counts[e];
    int mbase = blockIdx.y * 128;
    if (mbase >= cnt) return;
    int n0 = blockIdx.x * 64;
    int off = 0;
    for (int i = 0; i < e; ++i) off += counts[i];

    int t = threadIdx.x;
    int wid = t >> 6, lane = t & 63;
    int fl = lane & 15, kg = lane >> 4;
    int wm = (wid >> 1) * 64, wn = (wid & 1) * 32;

    // A staging role: 2 threads per row, 16 bf16 each
    int ar = t >> 1, ahalf = t & 1;
    int agrow = mbase + ar;
    int tok = (agrow < cnt) ? tlist[e * N_TOK + agrow] : 0;
    const unsigned short* asrc = xbf + (size_t)tok * C_DIM;

    // B staging role: wave -> (matrix, k-half); lane = n column
    int mat = wid >> 1, khalf = wid & 1;
    const float* W = (mat ? Wg : Wi) + (size_t)e * C_DIM * H_DIM;

    unsigned short* sA = smem;         // [128][40]
    unsigned short* sB = smem + 5120;  // [2][64][40] transposed: [n][k]

    f32x4 accu[4][2], accg[4][2];
    #pragma unroll
    for (int fm = 0; fm < 4; ++fm)
        #pragma unroll
        for (int fn = 0; fn < 2; ++fn) {
            accu[fm][fn] = (f32x4){0.f,0.f,0.f,0.f};
            accg[fm][fn] = (f32x4){0.f,0.f,0.f,0.f};
        }

    for (int k0 = 0; k0 < C_DIM; k0 += 32) {
        { // A: gathered x rows (bf16 already)
            const uint4* s = reinterpret_cast<const uint4*>(asrc + k0 + ahalf * 16);
            uint4 v0 = s[0], v1 = s[1];
            uint4* d = reinterpret_cast<uint4*>(sA + ar * 40 + ahalf * 16);
            d[0] = v0; d[1] = v1;
        }
        { // B: column-strided read (coalesced across lanes), cvt, vector LDS write
            union { unsigned short u[16]; uint4 v[2]; } col;
            const float* wp = W + (size_t)(k0 + khalf * 16) * H_DIM + n0 + lane;
            #pragma unroll
            for (int i = 0; i < 16; ++i) col.u[i] = f2bf(wp[(size_t)i * H_DIM]);
            uint4* d = reinterpret_cast<uint4*>(sB + mat * 2560 + lane * 40 + khalf * 16);
            d[0] = col.v[0]; d[1] = col.v[1];
        }
        __syncthreads();
        short8 a[4];
        #pragma unroll
        for (int fm = 0; fm < 4; ++fm)
            a[fm] = *reinterpret_cast<const short8*>(sA + (wm + fm * 16 + fl) * 40 + kg * 8);
        short8 bi[2], bg[2];
        #pragma unroll
        for (int fn = 0; fn < 2; ++fn) {
            bi[fn] = *reinterpret_cast<const short8*>(sB + (wn + fn * 16 + fl) * 40 + kg * 8);
            bg[fn] = *reinterpret_cast<const short8*>(sB + 2560 + (wn + fn * 16 + fl) * 40 + kg * 8);
        }
        #pragma unroll
        for (int fm = 0; fm < 4; ++fm)
            #pragma unroll
            for (int fn = 0; fn < 2; ++fn) {
                accu[fm][fn] = mfma16(a[fm], bi[fn], accu[fm][fn]);
                accg[fm][fn] = mfma16(a[fm], bg[fn], accg[fm][fn]);
            }
        __syncthreads();
    }

    // epilogue: h = silu(gate)*up -> LDS tile [128][72] -> vectorized global store
    unsigned short* sh = smem;
    #pragma unroll
    for (int fm = 0; fm < 4; ++fm)
        #pragma unroll
        for (int fn = 0; fn < 2; ++fn)
            #pragma unroll
            for (int j = 0; j < 4; ++j) {
                float uv = accu[fm][fn][j];
                float gv = accg[fm][fn][j];
                float hv = (gv / (1.f + expf(-gv))) * uv;
                int row = wm + fm * 16 + kg * 4 + j;
                int coln = wn + fn * 16 + fl;
                sh[row * 72 + coln] = f2bf(hv);
            }
    __syncthreads();
    if (agrow < cnt) {
        const uint4* s = reinterpret_cast<const uint4*>(sh + ar * 72 + ahalf * 32);
        uint4* d = reinterpret_cast<uint4*>(hbuf + (size_t)(off + agrow) * H_DIM + n0 + ahalf * 32);
        d[0] = s[0]; d[1] = s[1]; d[2] = s[2]; d[3] = s[3];
    }
}

// ---------------- K3: down GEMM + scatter ----------------
__global__ __launch_bounds__(256) void k_down(
    const unsigned short* __restrict__ hbuf, const float* __restrict__ Wo,
    const int* __restrict__ counts, const int* __restrict__ tlist,
    const float* __restrict__ combine, float* __restrict__ out)
{
    __shared__ unsigned short smem[7680]; // sA[128][40] + sB[64][40]
    __shared__ int stok[128];
    __shared__ float scw[128];
    int e = blockIdx.z;
    int cnt = counts[e];
    int mbase = blockIdx.y * 128;
    if (mbase >= cnt) return;
    int n0 = blockIdx.x * 64;
    int off = 0;
    for (int i = 0; i < e; ++i) off += counts[i];

    int t = threadIdx.x;
    int wid = t >> 6, lane = t & 63;
    int fl = lane & 15, kg = lane >> 4;
    int wm = (wid >> 1) * 64, wn = (wid & 1) * 32;

    if (t < 128) {
        int grow = mbase + t;
        int v = grow < cnt;
        int tk = v ? tlist[e * N_TOK + grow] : 0;
        stok[t] = tk;
        scw[t] = v ? combine[(size_t)tk * E_NUM + e] : 0.f;
    }

    int ar = t >> 1, ahalf = t & 1;
    int hr = off + mbase + ar; if (hr > N_TOK * 2 - 1) hr = N_TOK * 2 - 1;
    const unsigned short* asrc = hbuf + (size_t)hr * H_DIM;
    const float* W = Wo + (size_t)e * H_DIM * C_DIM;

    unsigned short* sA = smem;         // [128][40]
    unsigned short* sB = smem + 5120;  // [64][40] transposed: [n][k]

    f32x4 acc[4][2];
    #pragma unroll
    for (int fm = 0; fm < 4; ++fm)
        #pragma unroll
        for (int fn = 0; fn < 2; ++fn) acc[fm][fn] = (f32x4){0.f,0.f,0.f,0.f};

    for (int k0 = 0; k0 < H_DIM; k0 += 32) {
        {
            const uint4* s = reinterpret_cast<const uint4*>(asrc + k0 + ahalf * 16);
            uint4 v0 = s[0], v1 = s[1];
            uint4* d = reinterpret_cast<uint4*>(sA + ar * 40 + ahalf * 16);
            d[0] = v0; d[1] = v1;
        }
        { // B: wave w covers k rows w*8..w*8+7; lane = n column
            union { unsigned short u[8]; uint4 v; } col;
            const float* wp = W + (size_t)(k0 + wid * 8) * C_DIM + n0 + lane;
            #pragma unroll
            for (int i = 0; i < 8; ++i) col.u[i] = f2bf(wp[(size_t)i * C_DIM]);
            *reinterpret_cast<uint4*>(sB + lane * 40 + wid * 8) = col.v;
        }
        __syncthreads();
        short8 a[4], b[2];
        #pragma unroll
        for (int fm = 0; fm < 4; ++fm)
            a[fm] = *reinterpret_cast<const short8*>(sA + (wm + fm * 16 + fl) * 40 + kg * 8);
        #pragma unroll
        for (int fn = 0; fn < 2; ++fn)
            b[fn] = *reinterpret_cast<const short8*>(sB + (wn + fn * 16 + fl) * 40 + kg * 8);
        #pragma unroll
        for (int fm = 0; fm < 4; ++fm)
            #pragma unroll
            for (int fn = 0; fn < 2; ++fn)
                acc[fm][fn] = mfma16(a[fm], b[fn], acc[fm][fn]);
        __syncthreads();
    }

    #pragma unroll
    for (int fm = 0; fm < 4; ++fm)
        #pragma unroll
        for (int fn = 0; fn < 2; ++fn)
            #pragma unroll
            for (int j = 0; j < 4; ++j) {
                int rl = wm + fm * 16 + kg * 4 + j;
                if (mbase + rl < cnt) {
                    float v = acc[fm][fn][j] * scw[rl];
                    atomicAdd(out + (size_t)stok[rl] * C_DIM + n0 + wn + fn * 16 + fl, v);
                }
            }
}

extern "C" void kernel_launch(void* const* d_in, const int* in_sizes, int n_in,
                              void* d_out, int out_size, void* d_ws, size_t ws_size,
                              hipStream_t stream)
{
    const float* x     = (const float*)d_in[0];
    const float* wgate = (const float*)d_in[1];
    const float* wi    = (const float*)d_in[2];
    const float* wg    = (const float*)d_in[3];
    const float* wo    = (const float*)d_in[4];
    float* out = (float*)d_out;
    char* ws = (char*)d_ws;

    int* counts      = (int*)(ws + 0);
    int* tlist       = (int*)(ws + 1024);
    float* combine   = (float*)(ws + 263168);
    unsigned short* xbf = (unsigned short*)(ws + 1048576);
    unsigned short* h   = (unsigned short*)(ws + 17825792);

    hipMemsetAsync(counts, 0, 64, stream);
    hipMemsetAsync(d_out, 0, (size_t)out_size * sizeof(float), stream);

    k_gate<<<dim3(N_TOK / 4), dim3(256), 0, stream>>>(x, wgate, counts, tlist, combine, xbf);
    k_upgate<<<dim3(H_DIM / 64, N_TOK / 128, E_NUM), dim3(256), 0, stream>>>(
        xbf, wi, wg, counts, tlist, h);
    k_down<<<dim3(C_DIM / 64, N_TOK / 128, E_NUM), dim3(256), 0, stream>>>(
        h, wo, counts, tlist, combine, out);
}

// Round 3
// 766.007 us; speedup vs baseline: 1.1062x; 1.1062x over previous
//
#include <hip/hip_runtime.h>
#include <hip/hip_bf16.h>

// MoE top-2/8: N=8192 tokens, C=1024, H=2048.
// Fast path (needs ~191MB ws):
//   K0 k_wconv: wi/wg/wo fp32 -> bf16, transposed [n][k] 64x64 tiles with
//               XOR bank-swizzle baked into layout (chunk kc stored at cb = kc ^ (n&7)).
//   K1 k_gate:  fp32 gating (exact selection) + x->bf16 + per-expert token lists.
//   K2 k_upgate_f: grouped GEMM up&gate via global_load_lds staging (A gathered with
//               pre-swizzled per-lane source), SiLU -> h (bf16, packed rows).
//   K3 k_down_f: grouped GEMM down (h @ wo_t) * combine -> atomicAdd into zeroed out.
// Fallback path (ws < NEED): round-1 kernels (81MB layout).
//
// Round-3 fix: each global_load_lds issue stages 1KB/wave; round-2 issued only
// 1/4 of the required issues per K-step -> uninitialized LDS -> NaN. Now:
// k_upgate_f: 4 A-issues + 4 B-issues per wave per K-step (32KB total).
// k_down_f:   4 A-issues + 2 B-issues per wave per K-step (24KB total).

#define N_TOK 8192
#define C_DIM 1024
#define H_DIM 2048
#define E_NUM 8

typedef __attribute__((ext_vector_type(8))) short short8;
typedef __attribute__((ext_vector_type(4))) float f32x4;
typedef unsigned int u32;

__device__ __forceinline__ unsigned short f2bf(float f) {
    unsigned int u = __float_as_uint(f);
    unsigned int r = (u + 0x7FFFu + ((u >> 16) & 1u)) >> 16;
    return (unsigned short)r;
}

__device__ __forceinline__ f32x4 mfma16(short8 a, short8 b, f32x4 c) {
    return __builtin_amdgcn_mfma_f32_16x16x32_bf16(a, b, c, 0, 0, 0);
}

__device__ __forceinline__ void gl_lds16(const void* g, void* l) {
    __builtin_amdgcn_global_load_lds(
        (const __attribute__((address_space(1))) u32*)g,
        (__attribute__((address_space(3))) u32*)l, 16, 0, 0);
}

// ---------------- K1: gating ----------------
__global__ __launch_bounds__(256) void k_gate(
    const float* __restrict__ x, const float* __restrict__ wgate,
    int* __restrict__ counts, int* __restrict__ tlist,
    float* __restrict__ combine, unsigned short* __restrict__ xbf)
{
    int wid = threadIdx.x >> 6;
    int lane = threadIdx.x & 63;
    int token = blockIdx.x * 4 + wid;
    const float* xr = x + (size_t)token * C_DIM;
    unsigned short* xbr = xbf + (size_t)token * C_DIM;

    float p[E_NUM] = {0.f,0.f,0.f,0.f,0.f,0.f,0.f,0.f};
    #pragma unroll
    for (int i = 0; i < C_DIM / 64; ++i) {
        int c = i * 64 + lane;
        float xv = xr[c];
        xbr[c] = f2bf(xv);
        const float4* wr = reinterpret_cast<const float4*>(wgate + (size_t)c * E_NUM);
        float4 w0 = wr[0], w1 = wr[1];
        p[0] += xv * w0.x; p[1] += xv * w0.y; p[2] += xv * w0.z; p[3] += xv * w0.w;
        p[4] += xv * w1.x; p[5] += xv * w1.y; p[6] += xv * w1.z; p[7] += xv * w1.w;
    }
    #pragma unroll
    for (int e = 0; e < E_NUM; ++e) {
        #pragma unroll
        for (int s = 32; s > 0; s >>= 1) p[e] += __shfl_xor(p[e], s, 64);
    }
    if (lane == 0) {
        float m = p[0];
        #pragma unroll
        for (int e = 1; e < E_NUM; ++e) m = fmaxf(m, p[e]);
        float g[E_NUM]; float den = 0.f;
        #pragma unroll
        for (int e = 0; e < E_NUM; ++e) { g[e] = expf(p[e] - m); den += g[e]; }
        float inv = 1.f / den;
        #pragma unroll
        for (int e = 0; e < E_NUM; ++e) g[e] *= inv;
        int i1 = 0;
        #pragma unroll
        for (int e = 1; e < E_NUM; ++e) if (g[e] > g[i1]) i1 = e;
        int i2 = (i1 == 0) ? 1 : 0;
        #pragma unroll
        for (int e = 0; e < E_NUM; ++e) if (e != i1 && g[e] > g[i2]) i2 = e;
        #pragma unroll
        for (int e = 0; e < E_NUM; ++e)
            combine[(size_t)token * E_NUM + e] = (e == i1 || e == i2) ? g[e] : 0.f;
        int p1 = atomicAdd(&counts[i1], 1);
        tlist[i1 * N_TOK + p1] = token;
        int p2 = atomicAdd(&counts[i2], 1);
        tlist[i2 * N_TOK + p2] = token;
    }
}

// ---------------- K0: weight convert + transpose + swizzle-bake ----------------
// dst tile (8KB): 16B-chunk ci: n = ci>>3, cb = ci&7 holds source k-chunk kc = cb ^ (n&7)
__global__ __launch_bounds__(256) void k_wconv(
    const float* __restrict__ wi, const float* __restrict__ wg, const float* __restrict__ wo,
    unsigned short* __restrict__ wit, unsigned short* __restrict__ wgt, unsigned short* __restrict__ wot)
{
    __shared__ unsigned short sT[64 * 80];
    int m = blockIdx.z;
    int e = blockIdx.y;
    const float* src; unsigned short* dst; int N; int ktb;
    if (m == 0)      { src = wi; dst = wit; N = H_DIM; ktb = 4; }
    else if (m == 1) { src = wg; dst = wgt; N = H_DIM; ktb = 4; }
    else             { src = wo; dst = wot; N = C_DIM; ktb = 5; }
    int K = (m == 2) ? H_DIM : C_DIM;
    int tile = blockIdx.x;                 // 0..511 = nt*KT + kt
    int nt = tile >> ktb;
    int kt = tile & ((1 << ktb) - 1);
    src += (size_t)e * K * N + (size_t)(kt * 64) * N + nt * 64;
    dst += ((size_t)e * 512 + tile) * 4096;

    int t = threadIdx.x;
    int kl = t >> 2, nq = (t & 3) << 4;    // k row, n base (16 floats)
    const float4* s4 = reinterpret_cast<const float4*>(src + (size_t)kl * N + nq);
    #pragma unroll
    for (int q = 0; q < 4; ++q) {
        float4 v = s4[q];
        sT[(nq + q * 4 + 0) * 80 + kl] = f2bf(v.x);
        sT[(nq + q * 4 + 1) * 80 + kl] = f2bf(v.y);
        sT[(nq + q * 4 + 2) * 80 + kl] = f2bf(v.z);
        sT[(nq + q * 4 + 3) * 80 + kl] = f2bf(v.w);
    }
    __syncthreads();
    #pragma unroll
    for (int q = 0; q < 2; ++q) {
        int ci = t * 2 + q;
        int nl = ci >> 3;
        int kc = (ci & 7) ^ (nl & 7);
        uint4 v = *reinterpret_cast<const uint4*>(sT + nl * 80 + kc * 8);
        *reinterpret_cast<uint4*>((char*)dst + ci * 16) = v;
    }
}

// ---------------- K2 fast: up/gate GEMM + SiLU -> h ----------------
// BM=128, BN=64 (x2 matrices), BK=64, 4 waves (2x2). LDS 32KB: sA 16KB, sBu 8KB, sBg 8KB.
__global__ __launch_bounds__(256) void k_upgate_f(
    const unsigned short* __restrict__ xbf,
    const unsigned short* __restrict__ wit, const unsigned short* __restrict__ wgt,
    const int* __restrict__ counts, const int* __restrict__ tlist,
    unsigned short* __restrict__ hbuf)
{
    __shared__ unsigned short smem[16384];
    int e = blockIdx.z;
    int cnt = counts[e];
    int mbase = blockIdx.y * 128;
    if (mbase >= cnt) return;
    int nt = blockIdx.x;                   // 0..31
    int off = 0;
    for (int i = 0; i < e; ++i) off += counts[i];

    int t = threadIdx.x, w = t >> 6, lane = t & 63;
    int fl = lane & 15, kg = lane >> 4;
    int wm = (w >> 1) * 64, wn = (w & 1) * 32;

    // A staging: wave w stages rows w*32 + j*8 + (lane>>3), j=0..3; swizzled source
    int rsub = lane >> 3;                  // 0..7, == (row & 7) for all j
    int cb = lane & 7;
    int swz = (cb ^ rsub) << 4;            // byte offset of source k-chunk
    const char* aptr[4];
    #pragma unroll
    for (int j = 0; j < 4; ++j) {
        int r = w * 32 + j * 8 + rsub;
        int tok = (mbase + r < cnt) ? tlist[e * N_TOK + mbase + r] : 0;
        aptr[j] = (const char*)(xbf + (size_t)tok * C_DIM) + swz;
    }
    // B staging: wave w -> matrix (w>>1), half bc=(w&1); 4 x 1KB slices each
    int mat = w >> 1, bc = w & 1;
    const unsigned short* wtb = mat ? wgt : wit;
    const char* bptr = (const char*)wtb + ((size_t)e * 512 + (size_t)nt * 16) * 8192
                       + bc * 4096 + lane * 16;

    f32x4 accu[4][2], accg[4][2];
    #pragma unroll
    for (int fm = 0; fm < 4; ++fm)
        #pragma unroll
        for (int fn = 0; fn < 2; ++fn) {
            accu[fm][fn] = (f32x4){0.f,0.f,0.f,0.f};
            accg[fm][fn] = (f32x4){0.f,0.f,0.f,0.f};
        }

    for (int kt = 0; kt < 16; ++kt) {
        #pragma unroll
        for (int j = 0; j < 4; ++j)
            gl_lds16(aptr[j] + (kt << 7), smem + w * 2048 + j * 512);
        #pragma unroll
        for (int j = 0; j < 4; ++j)
            gl_lds16(bptr + (size_t)kt * 8192 + j * 1024,
                     smem + 8192 + mat * 4096 + bc * 2048 + j * 512);
        __syncthreads();
        #pragma unroll
        for (int kk = 0; kk < 2; ++kk) {
            short8 a[4], bu[2], bg[2];
            #pragma unroll
            for (int fm = 0; fm < 4; ++fm) {
                int r = wm + fm * 16 + fl;
                int xo = ((kk * 64 + kg * 16) ^ ((r & 7) << 4)) >> 1;
                a[fm] = *reinterpret_cast<const short8*>(smem + r * 64 + xo);
            }
            #pragma unroll
            for (int fn = 0; fn < 2; ++fn) {
                int n = wn + fn * 16 + fl;
                int xo = ((kk * 64 + kg * 16) ^ ((n & 7) << 4)) >> 1;
                bu[fn] = *reinterpret_cast<const short8*>(smem + 8192 + n * 64 + xo);
                bg[fn] = *reinterpret_cast<const short8*>(smem + 12288 + n * 64 + xo);
            }
            #pragma unroll
            for (int fm = 0; fm < 4; ++fm)
                #pragma unroll
                for (int fn = 0; fn < 2; ++fn) {
                    accu[fm][fn] = mfma16(a[fm], bu[fn], accu[fm][fn]);
                    accg[fm][fn] = mfma16(a[fm], bg[fn], accg[fm][fn]);
                }
        }
        __syncthreads();
    }

    // epilogue: h = silu(gate)*up -> LDS bounce [128][80] -> vectorized store (plain rows)
    unsigned short* sh = smem;
    #pragma unroll
    for (int fm = 0; fm < 4; ++fm)
        #pragma unroll
        for (int fn = 0; fn < 2; ++fn)
            #pragma unroll
            for (int j = 0; j < 4; ++j) {
                float uv = accu[fm][fn][j];
                float gv = accg[fm][fn][j];
                float hv = (gv / (1.f + expf(-gv))) * uv;
                int row = wm + fm * 16 + kg * 4 + j;
                int coln = wn + fn * 16 + fl;
                sh[row * 80 + coln] = f2bf(hv);
            }
    __syncthreads();
    int ar = t >> 1, ahalf = t & 1;
    if (mbase + ar < cnt) {
        const uint4* s = reinterpret_cast<const uint4*>(sh + ar * 80 + ahalf * 32);
        uint4* d = reinterpret_cast<uint4*>(hbuf + (size_t)(off + mbase + ar) * H_DIM + nt * 64 + ahalf * 32);
        d[0] = s[0]; d[1] = s[1]; d[2] = s[2]; d[3] = s[3];
    }
}

// ---------------- K3 fast: down GEMM + scatter ----------------
// BM=128, BN=64, BK=64, 4 waves (2x2). LDS 24KB: sA 16KB, sB 8KB.
__global__ __launch_bounds__(256) void k_down_f(
    const unsigned short* __restrict__ hbuf, const unsigned short* __restrict__ wot,
    const int* __restrict__ counts, const int* __restrict__ tlist,
    const float* __restrict__ combine, float* __restrict__ out)
{
    __shared__ unsigned short smem[12288];
    __shared__ int stok[128];
    __shared__ float scw[128];
    int e = blockIdx.z;
    int cnt = counts[e];
    int mbase = blockIdx.y * 128;
    if (mbase >= cnt) return;
    int nt = blockIdx.x;                   // 0..15
    int off = 0;
    for (int i = 0; i < e; ++i) off += counts[i];

    int t = threadIdx.x, w = t >> 6, lane = t & 63;
    int fl = lane & 15, kg = lane >> 4;
    int wm = (w >> 1) * 64, wn = (w & 1) * 32;

    if (t < 128) {
        int grow = mbase + t;
        int v = grow < cnt;
        int tk = v ? tlist[e * N_TOK + grow] : 0;
        stok[t] = tk;
        scw[t] = v ? combine[(size_t)tk * E_NUM + e] : 0.f;
    }

    int rsub = lane >> 3;
    int cb = lane & 7;
    int swz = (cb ^ rsub) << 4;
    const char* aptr[4];
    #pragma unroll
    for (int j = 0; j < 4; ++j) {
        int r = w * 32 + j * 8 + rsub;
        int hr = off + mbase + r;
        if (hr > N_TOK * 2 - 1) hr = N_TOK * 2 - 1;
        aptr[j] = (const char*)(hbuf + (size_t)hr * H_DIM) + swz;
    }
    const char* bptr = (const char*)wot + ((size_t)e * 512 + (size_t)nt * 32) * 8192
                       + w * 2048 + lane * 16;

    f32x4 acc[4][2];
    #pragma unroll
    for (int fm = 0; fm < 4; ++fm)
        #pragma unroll
        for (int fn = 0; fn < 2; ++fn) acc[fm][fn] = (f32x4){0.f,0.f,0.f,0.f};

    for (int kt = 0; kt < 32; ++kt) {
        #pragma unroll
        for (int j = 0; j < 4; ++j)
            gl_lds16(aptr[j] + (kt << 7), smem + w * 2048 + j * 512);
        #pragma unroll
        for (int j = 0; j < 2; ++j)
            gl_lds16(bptr + (size_t)kt * 8192 + j * 1024,
                     smem + 8192 + w * 1024 + j * 512);
        __syncthreads();
        #pragma unroll
        for (int kk = 0; kk < 2; ++kk) {
            short8 a[4], b[2];
            #pragma unroll
            for (int fm = 0; fm < 4; ++fm) {
                int r = wm + fm * 16 + fl;
                int xo = ((kk * 64 + kg * 16) ^ ((r & 7) << 4)) >> 1;
                a[fm] = *reinterpret_cast<const short8*>(smem + r * 64 + xo);
            }
            #pragma unroll
            for (int fn = 0; fn < 2; ++fn) {
                int n = wn + fn * 16 + fl;
                int xo = ((kk * 64 + kg * 16) ^ ((n & 7) << 4)) >> 1;
                b[fn] = *reinterpret_cast<const short8*>(smem + 8192 + n * 64 + xo);
            }
            #pragma unroll
            for (int fm = 0; fm < 4; ++fm)
                #pragma unroll
                for (int fn = 0; fn < 2; ++fn)
                    acc[fm][fn] = mfma16(a[fm], b[fn], acc[fm][fn]);
        }
        __syncthreads();
    }

    #pragma unroll
    for (int fm = 0; fm < 4; ++fm)
        #pragma unroll
        for (int fn = 0; fn < 2; ++fn)
            #pragma unroll
            for (int j = 0; j < 4; ++j) {
                int rl = wm + fm * 16 + kg * 4 + j;
                if (mbase + rl < cnt) {
                    float v = acc[fm][fn][j] * scw[rl];
                    atomicAdd(out + (size_t)stok[rl] * C_DIM + nt * 64 + wn + fn * 16 + fl, v);
                }
            }
}

// ================= Fallback (round-1) kernels =================
__global__ __launch_bounds__(256) void k_upgate_s(
    const unsigned short* __restrict__ xbf,
    const float* __restrict__ Wi, const float* __restrict__ Wg,
    const int* __restrict__ counts, const int* __restrict__ tlist,
    unsigned short* __restrict__ hbuf)
{
    __shared__ unsigned short smem[10240];
    int e = blockIdx.z;
    int cnt = counts[e];
    int mbase = blockIdx.y * 128;
    if (mbase >= cnt) return;
    int n0 = blockIdx.x * 64;
    int off = 0;
    for (int i = 0; i < e; ++i) off += counts[i];

    int t = threadIdx.x;
    int wid = t >> 6, lane = t & 63;
    int fl = lane & 15, kg = lane >> 4;
    int wm = (wid >> 1) * 64, wn = (wid & 1) * 32;

    int ar = t >> 1, ahalf = t & 1;
    int agrow = mbase + ar;
    int tok = (agrow < cnt) ? tlist[e * N_TOK + agrow] : 0;
    const unsigned short* asrc = xbf + (size_t)tok * C_DIM;

    int mat = wid >> 1, khalf = wid & 1;
    const float* W = (mat ? Wg : Wi) + (size_t)e * C_DIM * H_DIM;

    unsigned short* sA = smem;
    unsigned short* sB = smem + 5120;

    f32x4 accu[4][2], accg[4][2];
    #pragma unroll
    for (int fm = 0; fm < 4; ++fm)
        #pragma unroll
        for (int fn = 0; fn < 2; ++fn) {
            accu[fm][fn] = (f32x4){0.f,0.f,0.f,0.f};
            accg[fm][fn] = (f32x4){0.f,0.f,0.f,0.f};
        }

    for (int k0 = 0; k0 < C_DIM; k0 += 32) {
        {
            const uint4* s = reinterpret_cast<const uint4*>(asrc + k0 + ahalf * 16);
            uint4 v0 = s[0], v1 = s[1];
            uint4* d = reinterpret_cast<uint4*>(sA + ar * 40 + ahalf * 16);
            d[0] = v0; d[1] = v1;
        }
        {
            union { unsigned short u[16]; uint4 v[2]; } col;
            const float* wp = W + (size_t)(k0 + khalf * 16) * H_DIM + n0 + lane;
            #pragma unroll
            for (int i = 0; i < 16; ++i) col.u[i] = f2bf(wp[(size_t)i * H_DIM]);
            uint4* d = reinterpret_cast<uint4*>(sB + mat * 2560 + lane * 40 + khalf * 16);
            d[0] = col.v[0]; d[1] = col.v[1];
        }
        __syncthreads();
        short8 a[4];
        #pragma unroll
        for (int fm = 0; fm < 4; ++fm)
            a[fm] = *reinterpret_cast<const short8*>(sA + (wm + fm * 16 + fl) * 40 + kg * 8);
        short8 bi[2], bg[2];
        #pragma unroll
        for (int fn = 0; fn < 2; ++fn) {
            bi[fn] = *reinterpret_cast<const short8*>(sB + (wn + fn * 16 + fl) * 40 + kg * 8);
            bg[fn] = *reinterpret_cast<const short8*>(sB + 2560 + (wn + fn * 16 + fl) * 40 + kg * 8);
        }
        #pragma unroll
        for (int fm = 0; fm < 4; ++fm)
            #pragma unroll
            for (int fn = 0; fn < 2; ++fn) {
                accu[fm][fn] = mfma16(a[fm], bi[fn], accu[fm][fn]);
                accg[fm][fn] = mfma16(a[fm], bg[fn], accg[fm][fn]);
            }
        __syncthreads();
    }

    unsigned short* sh = smem;
    #pragma unroll
    for (int fm = 0; fm < 4; ++fm)
        #pragma unroll
        for (int fn = 0; fn < 2; ++fn)
            #pragma unroll
            for (int j = 0; j < 4; ++j) {
                float uv = accu[fm][fn][j];
                float gv = accg[fm][fn][j];
                float hv = (gv / (1.f + expf(-gv))) * uv;
                int row = wm + fm * 16 + kg * 4 + j;
                int coln = wn + fn * 16 + fl;
                sh[row * 72 + coln] = f2bf(hv);
            }
    __syncthreads();
    if (agrow < cnt) {
        const uint4* s = reinterpret_cast<const uint4*>(sh + ar * 72 + ahalf * 32);
        uint4* d = reinterpret_cast<uint4*>(hbuf + (size_t)(off + agrow) * H_DIM + n0 + ahalf * 32);
        d[0] = s[0]; d[1] = s[1]; d[2] = s[2]; d[3] = s[3];
    }
}

__global__ __launch_bounds__(256) void k_down_s(
    const unsigned short* __restrict__ hbuf, const float* __restrict__ Wo,
    const int* __restrict__ counts, const int* __restrict__ tlist,
    const float* __restrict__ combine, float* __restrict__ out)
{
    __shared__ unsigned short smem[7680];
    __shared__ int stok[128];
    __shared__ float scw[128];
    int e = blockIdx.z;
    int cnt = counts[e];
    int mbase = blockIdx.y * 128;
    if (mbase >= cnt) return;
    int n0 = blockIdx.x * 64;
    int off = 0;
    for (int i = 0; i < e; ++i) off += counts[i];

    int t = threadIdx.x;
    int wid = t >> 6, lane = t & 63;
    int fl = lane & 15, kg = lane >> 4;
    int wm = (wid >> 1) * 64, wn = (wid & 1) * 32;

    if (t < 128) {
        int grow = mbase + t;
        int v = grow < cnt;
        int tk = v ? tlist[e * N_TOK + grow] : 0;
        stok[t] = tk;
        scw[t] = v ? combine[(size_t)tk * E_NUM + e] : 0.f;
    }

    int ar = t >> 1, ahalf = t & 1;
    int hr = off + mbase + ar; if (hr > N_TOK * 2 - 1) hr = N_TOK * 2 - 1;
    const unsigned short* asrc = hbuf + (size_t)hr * H_DIM;
    const float* W = Wo + (size_t)e * H_DIM * C_DIM;

    unsigned short* sA = smem;
    unsigned short* sB = smem + 5120;

    f32x4 acc[4][2];
    #pragma unroll
    for (int fm = 0; fm < 4; ++fm)
        #pragma unroll
        for (int fn = 0; fn < 2; ++fn) acc[fm][fn] = (f32x4){0.f,0.f,0.f,0.f};

    for (int k0 = 0; k0 < H_DIM; k0 += 32) {
        {
            const uint4* s = reinterpret_cast<const uint4*>(asrc + k0 + ahalf * 16);
            uint4 v0 = s[0], v1 = s[1];
            uint4* d = reinterpret_cast<uint4*>(sA + ar * 40 + ahalf * 16);
            d[0] = v0; d[1] = v1;
        }
        {
            union { unsigned short u[8]; uint4 v; } col;
            const float* wp = W + (size_t)(k0 + wid * 8) * C_DIM + n0 + lane;
            #pragma unroll
            for (int i = 0; i < 8; ++i) col.u[i] = f2bf(wp[(size_t)i * C_DIM]);
            *reinterpret_cast<uint4*>(sB + lane * 40 + wid * 8) = col.v;
        }
        __syncthreads();
        short8 a[4], b[2];
        #pragma unroll
        for (int fm = 0; fm < 4; ++fm)
            a[fm] = *reinterpret_cast<const short8*>(sA + (wm + fm * 16 + fl) * 40 + kg * 8);
        #pragma unroll
        for (int fn = 0; fn < 2; ++fn)
            b[fn] = *reinterpret_cast<const short8*>(sB + (wn + fn * 16 + fl) * 40 + kg * 8);
        #pragma unroll
        for (int fm = 0; fm < 4; ++fm)
            #pragma unroll
            for (int fn = 0; fn < 2; ++fn)
                acc[fm][fn] = mfma16(a[fm], b[fn], acc[fm][fn]);
        __syncthreads();
    }

    #pragma unroll
    for (int fm = 0; fm < 4; ++fm)
        #pragma unroll
        for (int fn = 0; fn < 2; ++fn)
            #pragma unroll
            for (int j = 0; j < 4; ++j) {
                int rl = wm + fm * 16 + kg * 4 + j;
                if (mbase + rl < cnt) {
                    float v = acc[fm][fn][j] * scw[rl];
                    atomicAdd(out + (size_t)stok[rl] * C_DIM + n0 + wn + fn * 16 + fl, v);
                }
            }
}

extern "C" void kernel_launch(void* const* d_in, const int* in_sizes, int n_in,
                              void* d_out, int out_size, void* d_ws, size_t ws_size,
                              hipStream_t stream)
{
    const float* x     = (const float*)d_in[0];
    const float* wgate = (const float*)d_in[1];
    const float* wi    = (const float*)d_in[2];
    const float* wg    = (const float*)d_in[3];
    const float* wo    = (const float*)d_in[4];
    float* out = (float*)d_out;
    char* ws = (char*)d_ws;

    int* counts      = (int*)(ws + 0);
    int* tlist       = (int*)(ws + 1024);
    float* combine   = (float*)(ws + 263168);
    unsigned short* xbf = (unsigned short*)(ws + 1048576);
    unsigned short* h   = (unsigned short*)(ws + 17825792);

    const size_t NEED = 190840832ull; // misc + xbf 16MB + h 64.5MB + wt 96MB

    hipMemsetAsync(counts, 0, 64, stream);
    hipMemsetAsync(d_out, 0, (size_t)out_size * sizeof(float), stream);

    if (ws_size >= NEED) {
        unsigned short* wit = (unsigned short*)(ws + 90177536ull);
        unsigned short* wgt = (unsigned short*)(ws + 123731968ull);
        unsigned short* wot = (unsigned short*)(ws + 157286400ull);
        k_wconv<<<dim3(512, 8, 3), dim3(256), 0, stream>>>(wi, wg, wo, wit, wgt, wot);
        k_gate<<<dim3(N_TOK / 4), dim3(256), 0, stream>>>(x, wgate, counts, tlist, combine, xbf);
        k_upgate_f<<<dim3(32, N_TOK / 128, E_NUM), dim3(256), 0, stream>>>(
            xbf, wit, wgt, counts, tlist, h);
        k_down_f<<<dim3(16, N_TOK / 128, E_NUM), dim3(256), 0, stream>>>(
            h, wot, counts, tlist, combine, out);
    } else {
        k_gate<<<dim3(N_TOK / 4), dim3(256), 0, stream>>>(x, wgate, counts, tlist, combine, xbf);
        k_upgate_s<<<dim3(H_DIM / 64, N_TOK / 128, E_NUM), dim3(256), 0, stream>>>(
            xbf, wi, wg, counts, tlist, h);
        k_down_s<<<dim3(C_DIM / 64, N_TOK / 128, E_NUM), dim3(256), 0, stream>>>(
            h, wo, counts, tlist, combine, out);
    }
}